// Round 3
// baseline (813.981 us; speedup 1.0000x reference)
//
#include <hip/hip_runtime.h>
#include <math.h>

#define NBAGS 2048
#define CROWS 64
#define IND   512
#define TAUV  0.95f
#define KDROP 44   // int(64*0.7)

typedef _Float16 h8  __attribute__((ext_vector_type(8)));
typedef _Float16 h4  __attribute__((ext_vector_type(4)));
typedef float    f16v __attribute__((ext_vector_type(16)));

#define MFMA16(a, b, c) __builtin_amdgcn_mfma_f32_32x32x16_f16(a, b, c, 0, 0, 0)

// ---------------------------------------------------------------------------
// Fragment-order layout for an MFMA operand plane (A: [m][k], B: [n][k]).
//   addr = (tile*nkt + (k>>4))*528 + (idx&31)*8 + ((k>>3)&1)*264 + (k&7)
// ---------------------------------------------------------------------------
__device__ __forceinline__ int frag_roff(int lane, int tile, int t, int nkt) {
  return (tile * nkt + t) * 528 + (lane & 31) * 8 + (lane >> 5) * 264;
}

// ws element offsets (in _Float16 units). plane = (N/32)*nkt*528.
#define W1HI 0
#define W1LO 135168
#define W2HI 270336
#define W2LO 337920
#define W3HI 405504
#define W3LO 439296
#define D1HI 473088
#define D1LO 489984
#define D2HI 506880
#define D2LO 515328
#define WS_ELS 523776  // ~1.05 MB

__global__ __launch_bounds__(256) void prep_weights(
    const float* __restrict__ W1, const float* __restrict__ W2,
    const float* __restrict__ W3, const float* __restrict__ D1,
    const float* __restrict__ D2, _Float16* __restrict__ ws)
{
  int e = blockIdx.x * 256 + threadIdx.x;
  const float* src; int local, nlog, nkt, offH, offL;
  if (e < 131072)      { src = W1; local = e;          nlog = 8; nkt = 32; offH = W1HI; offL = W1LO; }
  else if (e < 196608) { src = W2; local = e - 131072; nlog = 8; nkt = 16; offH = W2HI; offL = W2LO; }
  else if (e < 229376) { src = W3; local = e - 196608; nlog = 7; nkt = 16; offH = W3HI; offL = W3LO; }
  else if (e < 245760) { src = D1; local = e - 229376; nlog = 7; nkt = 8;  offH = D1HI; offL = D1LO; }
  else if (e < 253952) { src = D2; local = e - 245760; nlog = 6; nkt = 8;  offH = D2HI; offL = D2LO; }
  else return;
  int k = local >> nlog;
  int n = local & ((1 << nlog) - 1);
  float w = src[local];
  _Float16 hi = (_Float16)w;
  _Float16 lo = (_Float16)(w - (float)hi);
  int addr = ((n >> 5) * nkt + (k >> 4)) * 528 + (n & 31) * 8 + ((k >> 3) & 1) * 264 + (k & 7);
  ws[offH + addr] = hi;
  ws[offL + addr] = lo;
}

// ---------------------------------------------------------------------------
// Generic phase, 16 waves: wave -> (kh, tile=(mt,nt)). Optional 2-way K-split
// (KS=2) reducing through float4 LDS scratch placed in a DEAD region:
//   compute -> bar (input dead) -> kh>=1 scratch write -> bar -> kh0 reduce
//   -> [XBAR bar if scratch aliases output] -> kh0 epilogue -> bar
// Output may alias input (in-place ping-pong): bar1 separates last A-read
// from first O-write.
// ---------------------------------------------------------------------------
template<int NKT_TOT, int NTILES, int KS, int XBAR, int ACT>
__device__ __forceinline__ void gemm_phase(
    const _Float16* __restrict__ bHi, const _Float16* __restrict__ bLo,
    const float* __restrict__ bias,
    const _Float16* aHi, const _Float16* aLo,
    _Float16* oHi, _Float16* oLo, float4* scratch,
    int wave, int lane)
{
  constexpr int TILES = 2 * NTILES;
  constexpr int NKTP  = NKT_TOT / KS;
  constexpr int ONKT  = NTILES * 2;
  const int tile = wave & (TILES - 1);
  const int kh   = wave / TILES;
  const int mt = tile & 1, nt = tile >> 1;
  f16v acc = {};
  if (kh < KS) {
    const int t0 = kh * NKTP;
    h8 bhc, blc, bhn, bln, ahc, alc;
    { int bo = frag_roff(lane, nt, t0, NKT_TOT);
      bhc = *(const h8*)(bHi + bo); blc = *(const h8*)(bLo + bo); }
    if constexpr (NKTP > 1) {
      int bo = frag_roff(lane, nt, t0 + 1, NKT_TOT);
      bhn = *(const h8*)(bHi + bo); bln = *(const h8*)(bLo + bo);
    }
    { int ao = frag_roff(lane, mt, t0, NKT_TOT);
      ahc = *(const h8*)(aHi + ao); alc = *(const h8*)(aLo + ao); }
#pragma unroll
    for (int t = 0; t < NKTP; ++t) {
      h8 bhf, blf, ahn, aln;
      if (t + 2 < NKTP) {
        int bo = frag_roff(lane, nt, t0 + t + 2, NKT_TOT);
        bhf = *(const h8*)(bHi + bo); blf = *(const h8*)(bLo + bo);
      }
      if (t + 1 < NKTP) {
        int ao = frag_roff(lane, mt, t0 + t + 1, NKT_TOT);
        ahn = *(const h8*)(aHi + ao); aln = *(const h8*)(aLo + ao);
      }
      acc = MFMA16(ahc, bhc, acc);
      acc = MFMA16(ahc, blc, acc);
      acc = MFMA16(alc, bhc, acc);
      bhc = bhn; blc = bln; bhn = bhf; bln = blf; ahc = ahn; alc = aln;
    }
  }
  __syncthreads();   // bar1: all A reads done -> input region dead
  if constexpr (KS > 1) {
    if (kh >= 1 && kh < KS) {
#pragma unroll
      for (int r = 0; r < 4; ++r) {
        float4 v = { acc[4*r], acc[4*r+1], acc[4*r+2], acc[4*r+3] };
        scratch[((tile * (KS - 1) + (kh - 1)) * 4 + r) * 64 + lane] = v;
      }
    }
    __syncthreads();  // bar2: scratch visible
    if (kh == 0) {
#pragma unroll
      for (int s = 0; s < KS - 1; ++s)
#pragma unroll
        for (int r = 0; r < 4; ++r) {
          float4 v = scratch[((tile * (KS - 1) + s) * 4 + r) * 64 + lane];
          acc[4*r] += v.x; acc[4*r+1] += v.y; acc[4*r+2] += v.z; acc[4*r+3] += v.w;
        }
    }
    if constexpr (XBAR) __syncthreads();  // bar3: scratch reads before O writes
  }
  if (kh == 0) {
    // epilogue: C/D layout col=lane&31, row=(r&3)+8*(r>>2)+4*(lane>>5)
    int n = nt * 32 + (lane & 31);
    float bs = bias[n];
    int t2 = n >> 4, kg = (n >> 3) & 1, j = n & 7;
#pragma unroll
    for (int r = 0; r < 16; ++r) {
      int row = (r & 3) + 8 * (r >> 2) + 4 * (lane >> 5);
      int m = mt * 32 + row;
      float v = acc[r] + bs;
      v = (ACT == 0) ? fmaxf(v, 0.0f) : (1.0f / (1.0f + __expf(-v)));
      _Float16 hi = (_Float16)v;
      _Float16 lo = (_Float16)(v - (float)hi);
      int addr = ((m >> 5) * ONKT + t2) * 528 + (m & 31) * 8 + kg * 264 + j;
      oHi[addr] = hi;
      oLo[addr] = lo;
    }
  }
  __syncthreads();
}

// ---------------------------------------------------------------------------
// Phase 1: x (fp32 HBM) @ W1 -> h1. 128-k chunks (4 chunks), double-buffered
// staging. Epilogue writes h1 OVER the (dead) x staging buffers.
// ---------------------------------------------------------------------------
__device__ __forceinline__ void phase1(
    const float* __restrict__ xg,
    const _Float16* __restrict__ bHi, const _Float16* __restrict__ bLo,
    const float* __restrict__ bias,
    _Float16* xs,                 // staging: 2 bufs x 16896 els (hi 8448 + lo 8448)
    _Float16* oHi, _Float16* oLo, // h1 planes (ONKT=16) -- alias xs bufs
    int tid, int wave, int lane)
{
  const int mt = wave & 1, nt = wave >> 1;
  f16v acc = {};
  float4 xv[2];

  auto loadx = [&](int c) {
#pragma unroll
    for (int it = 0; it < 2; ++it) {
      int flat = it * 1024 + tid;
      int row = flat >> 5, c4 = flat & 31;
      xv[it] = *(const float4*)(xg + row * 512 + c * 128 + c4 * 4);
    }
  };
  auto storex = [&](int c) {
    _Float16* sHi = xs + (c & 1) * 16896;
    _Float16* sLo = sHi + 8448;
#pragma unroll
    for (int it = 0; it < 2; ++it) {
      int flat = it * 1024 + tid;
      int row = flat >> 5, c4 = flat & 31;
      int t = c4 >> 2, kg = (c4 >> 1) & 1, j0 = (c4 & 1) * 4;
      int addr = ((row >> 5) * 8 + t) * 528 + (row & 31) * 8 + kg * 264 + j0;
      float4 v = xv[it];
      h4 hi, lo;
      hi[0] = (_Float16)v.x; lo[0] = (_Float16)(v.x - (float)hi[0]);
      hi[1] = (_Float16)v.y; lo[1] = (_Float16)(v.y - (float)hi[1]);
      hi[2] = (_Float16)v.z; lo[2] = (_Float16)(v.z - (float)hi[2]);
      hi[3] = (_Float16)v.w; lo[3] = (_Float16)(v.w - (float)hi[3]);
      *(h4*)(sHi + addr) = hi;
      *(h4*)(sLo + addr) = lo;
    }
  };

  // B prefetch depth-2 over the full 32-t plane (rotation carries across chunks)
  h8 bhc, blc, bhn, bln;
  { int bo = frag_roff(lane, nt, 0, 32);
    bhc = *(const h8*)(bHi + bo); blc = *(const h8*)(bLo + bo); }
  { int bo = frag_roff(lane, nt, 1, 32);
    bhn = *(const h8*)(bHi + bo); bln = *(const h8*)(bLo + bo); }

  loadx(0);
  storex(0);
  __syncthreads();
  for (int c = 0; c < 4; ++c) {
    if (c < 3) loadx(c + 1);   // HBM loads in flight across the chunk's MFMA
    const _Float16* sHi = xs + (c & 1) * 16896;
    const _Float16* sLo = sHi + 8448;
    h8 ahc, alc;
    { int ao = frag_roff(lane, mt, 0, 8);
      ahc = *(const h8*)(sHi + ao); alc = *(const h8*)(sLo + ao); }
#pragma unroll
    for (int t = 0; t < 8; ++t) {
      int tg = c * 8 + t;
      h8 bhf, blf, ahn, aln;
      if (tg + 2 < 32) {
        int bo = frag_roff(lane, nt, tg + 2, 32);
        bhf = *(const h8*)(bHi + bo); blf = *(const h8*)(bLo + bo);
      }
      if (t + 1 < 8) {
        int ao = frag_roff(lane, mt, t + 1, 8);
        ahn = *(const h8*)(sHi + ao); aln = *(const h8*)(sLo + ao);
      }
      acc = MFMA16(ahc, bhc, acc);
      acc = MFMA16(ahc, blc, acc);
      acc = MFMA16(alc, bhc, acc);
      bhc = bhn; blc = bln; bhn = bhf; bln = blf; ahc = ahn; alc = aln;
    }
    if (c < 3) storex(c + 1);
    __syncthreads();
  }
  // epilogue -> h1 planes (ONKT = 16), overwriting x staging (dead)
  int n = nt * 32 + (lane & 31);
  float bs = bias[n];
  int t2 = n >> 4, kg = (n >> 3) & 1, j = n & 7;
#pragma unroll
  for (int r = 0; r < 16; ++r) {
    int row = (r & 3) + 8 * (r >> 2) + 4 * (lane >> 5);
    int m = mt * 32 + row;
    float v = fmaxf(acc[r] + bs, 0.0f);
    _Float16 hi = (_Float16)v;
    _Float16 lo = (_Float16)(v - (float)hi);
    int addr = ((m >> 5) * 16 + t2) * 528 + (m & 31) * 8 + kg * 264 + j;
    oHi[addr] = hi;
    oLo[addr] = lo;
  }
  __syncthreads();
}

#define BUFELS 33792  // total dynamic LDS elements (67584 B) -> 2 blocks/CU

__global__ __launch_bounds__(1024, 8) void bagnet_mfma(
    const float* __restrict__ gx, const float* __restrict__ gm,
    const float* __restrict__ gu,
    const float* __restrict__ gb1, const float* __restrict__ gb2,
    const float* __restrict__ gb3, const float* __restrict__ gdb1,
    const float* __restrict__ gdb2, const float* __restrict__ gD3,
    const float* __restrict__ gdb3, const float* __restrict__ gE,
    const float* __restrict__ geb, const _Float16* __restrict__ ws,
    float* __restrict__ outw, float* __restrict__ outv)
{
  extern __shared__ _Float16 lds[];
  __shared__ float sWf[64], sPart[2];
  const int tid = threadIdx.x, bag = blockIdx.x;
  const int wave = tid >> 6, lane = tid & 63;

  // LDS liveness plan (els):
  //  P1: x staging dbuf [0,33792) -> h1 hi [0,16896) lo [16896,33792)
  //  P2: h1 -> h2 in place (KS=1)
  //  P3: h2 -> h  hi [0,8448) lo [8448,16896); scratch 32KB in dead h2-lo [16896,..)
  //  P4: h  -> d1 hi [16896,25344) lo [25344,33792); scratch 32KB aliases output
  //      region -> XBAR=1 (extra barrier orders scratch reads before O writes)
  //  P5: d1 -> d2 hi [16896,21120) lo [21120,25344); scratch 16KB in dead
  //      d1-lo [25344,..); h preserved at [0,16896) for the tail
  phase1(gx + (size_t)bag * CROWS * IND, ws + W1HI, ws + W1LO, gb1,
         lds, lds, lds + 16896, tid, wave, lane);
  gemm_phase<16, 8, 1, 0, 0>(ws + W2HI, ws + W2LO, gb2, lds, lds + 16896,
                             lds, lds + 16896, nullptr, wave, lane);
  gemm_phase<16, 4, 2, 0, 0>(ws + W3HI, ws + W3LO, gb3, lds, lds + 16896,
                             lds, lds + 8448, (float4*)(lds + 16896), wave, lane);
  gemm_phase<8, 4, 2, 1, 1>(ws + D1HI, ws + D1LO, gdb1, lds, lds + 8448,
                            lds + 16896, lds + 25344, (float4*)(lds + 16896), wave, lane);
  gemm_phase<8, 2, 2, 0, 1>(ws + D2HI, ws + D2LO, gdb2, lds + 16896, lds + 25344,
                            lds + 16896, lds + 21120, (float4*)(lds + 25344), wave, lane);

  const _Float16* d2H = lds + 16896;
  const _Float16* d2L = lds + 21120;
  const _Float16* hH  = lds;
  const _Float16* hL  = lds + 8448;

  // -------- tail: logits + gumbel softmax + top-20 keep, wave 0 only, -------
  // -------- shuffle butterflies, zero internal barriers ---------------------
  if (wave == 0) {
    // logits: lane = bag-row; vectorized b128 reads of d2 (8 k's per load)
    float a = gdb3[0];
#pragma unroll
    for (int kg8 = 0; kg8 < 8; ++kg8) {
      int k0 = kg8 * 8;
      int addr = ((lane >> 5) * 4 + (k0 >> 4)) * 528 + (lane & 31) * 8 + ((k0 >> 3) & 1) * 264;
      h8 vh = *(const h8*)(d2H + addr);
      h8 vl = *(const h8*)(d2L + addr);
#pragma unroll
      for (int j = 0; j < 8; ++j)
        a = fmaf((float)vh[j] + (float)vl[j], gD3[k0 + j], a);
    }
    float logit = gm[(size_t)bag * CROWS + lane] * a;
    float uu = gu[(size_t)bag * CROWS + lane];
    float g = -logf(-logf(uu));
    float z = (logit + g) * (1.0f / TAUV);
    // softmax over the 64 lanes
    float mx = z;
#pragma unroll
    for (int o = 32; o; o >>= 1) mx = fmaxf(mx, __shfl_xor(mx, o));
    float ex = __expf(z - mx);
    float s = ex;
#pragma unroll
    for (int o = 32; o; o >>= 1) s += __shfl_xor(s, o);
    float w2 = ex / s;
    // stable rank (ascending, tie by index): keep iff rank >= KDROP
    int cnt = 0;
    for (int j = 0; j < 64; ++j) {
      float vj = __shfl(w2, j);
      cnt += (vj < w2) || (vj == w2 && j < lane);
    }
    int keep = (cnt >= KDROP) ? 1 : 0;
    // re-softmax over kept entries
    float wk = keep ? w2 : -1e30f;
    float mk = wk;
#pragma unroll
    for (int o = 32; o; o >>= 1) mk = fmaxf(mk, __shfl_xor(mk, o));
    float e2 = keep ? __expf(w2 - mk) : 0.0f;
    float s2 = e2;
#pragma unroll
    for (int o = 32; o; o >>= 1) s2 += __shfl_xor(s2, o);
    float wf = keep ? (e2 / s2) : 0.0f;
    sWf[lane] = wf;
    outw[(size_t)bag * CROWS + lane] = wf;
  }
  __syncthreads();
  // agg = w @ h ; out = agg @ E + eb   (waves 0-1, butterfly-reduced)
  if (tid < 128) {
    float a = 0.0f;
    for (int r = 0; r < CROWS; ++r) {
      int addr = ((r >> 5) * 8 + (tid >> 4)) * 528 + (r & 31) * 8 + ((tid >> 3) & 1) * 264 + (tid & 7);
      a = fmaf(sWf[r], (float)hH[addr] + (float)hL[addr], a);
    }
    float p = a * gE[tid];
#pragma unroll
    for (int o = 32; o; o >>= 1) p += __shfl_xor(p, o);
    if (lane == 0) sPart[wave] = p;
  }
  __syncthreads();
  if (tid == 0) outv[bag] = geb[0] + sPart[0] + sPart[1];
}

extern "C" void kernel_launch(void* const* d_in, const int* in_sizes, int n_in,
                              void* d_out, int out_size, void* d_ws, size_t ws_size,
                              hipStream_t stream) {
  (void)in_sizes; (void)n_in; (void)out_size; (void)ws_size;
  const float* x   = (const float*)d_in[0];
  const float* m   = (const float*)d_in[1];
  const float* u   = (const float*)d_in[2];
  const float* W1  = (const float*)d_in[3];
  const float* b1  = (const float*)d_in[4];
  const float* W2  = (const float*)d_in[5];
  const float* b2  = (const float*)d_in[6];
  const float* W3  = (const float*)d_in[7];
  const float* b3  = (const float*)d_in[8];
  const float* D1  = (const float*)d_in[9];
  const float* db1 = (const float*)d_in[10];
  const float* D2  = (const float*)d_in[11];
  const float* db2 = (const float*)d_in[12];
  const float* D3  = (const float*)d_in[13];
  const float* db3 = (const float*)d_in[14];
  const float* E   = (const float*)d_in[15];
  const float* eb  = (const float*)d_in[16];
  float* outw = (float*)d_out;
  float* outv = outw + (size_t)NBAGS * CROWS;
  _Float16* ws = (_Float16*)d_ws;

  prep_weights<<<992, 256, 0, stream>>>(W1, W2, W3, D1, D2, ws);

  const size_t smem = (size_t)BUFELS * sizeof(_Float16);  // 67584 B
  (void)hipFuncSetAttribute((const void*)bagnet_mfma,
                            hipFuncAttributeMaxDynamicSharedMemorySize, (int)smem);
  bagnet_mfma<<<NBAGS, 1024, smem, stream>>>(
      x, m, u, b1, b2, b3, db1, db2, D3, db3, E, eb, ws, outw, outv);
}

// Round 4
// 789.678 us; speedup vs baseline: 1.0308x; 1.0308x over previous
//
#include <hip/hip_runtime.h>
#include <math.h>

#define NBAGS 2048
#define CROWS 64
#define IND   512
#define TAUV  0.95f
#define KDROP 44   // int(64*0.7)

typedef _Float16 h8  __attribute__((ext_vector_type(8)));
typedef _Float16 h4  __attribute__((ext_vector_type(4)));
typedef float    f16v __attribute__((ext_vector_type(16)));

#define MFMA16(a, b, c) __builtin_amdgcn_mfma_f32_32x32x16_f16(a, b, c, 0, 0, 0)

// ---------------------------------------------------------------------------
// Fragment-order layout for an MFMA operand plane (A: [m][k], B: [n][k]).
//   addr = (tile*nkt + (k>>4))*528 + (idx&31)*8 + ((k>>3)&1)*264 + (k&7)
// ---------------------------------------------------------------------------
__device__ __forceinline__ int frag_roff(int lane, int tile, int t, int nkt) {
  return (tile * nkt + t) * 528 + (lane & 31) * 8 + (lane >> 5) * 264;
}

// ws element offsets (in _Float16 units). plane = (N/32)*nkt*528.
#define W1HI 0
#define W1LO 135168
#define W2HI 270336
#define W2LO 337920
#define W3HI 405504
#define W3LO 439296
#define D1HI 473088
#define D1LO 489984
#define D2HI 506880
#define D2LO 515328
#define WS_ELS 523776  // ~1.05 MB

__global__ __launch_bounds__(256) void prep_weights(
    const float* __restrict__ W1, const float* __restrict__ W2,
    const float* __restrict__ W3, const float* __restrict__ D1,
    const float* __restrict__ D2, _Float16* __restrict__ ws)
{
  int e = blockIdx.x * 256 + threadIdx.x;
  const float* src; int local, nlog, nkt, offH, offL;
  if (e < 131072)      { src = W1; local = e;          nlog = 8; nkt = 32; offH = W1HI; offL = W1LO; }
  else if (e < 196608) { src = W2; local = e - 131072; nlog = 8; nkt = 16; offH = W2HI; offL = W2LO; }
  else if (e < 229376) { src = W3; local = e - 196608; nlog = 7; nkt = 16; offH = W3HI; offL = W3LO; }
  else if (e < 245760) { src = D1; local = e - 229376; nlog = 7; nkt = 8;  offH = D1HI; offL = D1LO; }
  else if (e < 253952) { src = D2; local = e - 245760; nlog = 6; nkt = 8;  offH = D2HI; offL = D2LO; }
  else return;
  int k = local >> nlog;
  int n = local & ((1 << nlog) - 1);
  float w = src[local];
  _Float16 hi = (_Float16)w;
  _Float16 lo = (_Float16)(w - (float)hi);
  int addr = ((n >> 5) * nkt + (k >> 4)) * 528 + (n & 31) * 8 + ((k >> 3) & 1) * 264 + (k & 7);
  ws[offH + addr] = hi;
  ws[offL + addr] = lo;
}

// ---------------------------------------------------------------------------
// Generic phase, 16 waves, wave -> tile=(mt,nt). No K-split (co-resident
// blocks cover latency). Output may alias input: a barrier separates
// last A-read from first epilogue write (in-place activation ping-pong).
// ---------------------------------------------------------------------------
template<int NKT_TOT, int NTILES, int ACT>   // NKT_TOT=K/16, NTILES=N/32
__device__ __forceinline__ void gemm_phase(
    const _Float16* __restrict__ bHi, const _Float16* __restrict__ bLo,
    const float* __restrict__ bias,
    const _Float16* aHi, const _Float16* aLo,
    _Float16* oHi, _Float16* oLo,
    int wave, int lane)
{
  constexpr int TILES = 2 * NTILES;
  constexpr int ONKT  = NTILES * 2;
  const int tile = wave & (TILES - 1);
  const int kh   = wave / TILES;       // kh > 0 waves idle (small phases)
  const int mt = tile & 1, nt = tile >> 1;
  f16v acc = {};
  if (kh == 0) {
    h8 bhc, blc, bhn, bln, ahc, alc;
    { int bo = frag_roff(lane, nt, 0, NKT_TOT);
      bhc = *(const h8*)(bHi + bo); blc = *(const h8*)(bLo + bo); }
    if constexpr (NKT_TOT > 1) {
      int bo = frag_roff(lane, nt, 1, NKT_TOT);
      bhn = *(const h8*)(bHi + bo); bln = *(const h8*)(bLo + bo);
    }
    { int ao = frag_roff(lane, mt, 0, NKT_TOT);
      ahc = *(const h8*)(aHi + ao); alc = *(const h8*)(aLo + ao); }
#pragma unroll
    for (int t = 0; t < NKT_TOT; ++t) {
      h8 bhf, blf, ahn, aln;
      if (t + 2 < NKT_TOT) {
        int bo = frag_roff(lane, nt, t + 2, NKT_TOT);
        bhf = *(const h8*)(bHi + bo); blf = *(const h8*)(bLo + bo);
      }
      if (t + 1 < NKT_TOT) {
        int ao = frag_roff(lane, mt, t + 1, NKT_TOT);
        ahn = *(const h8*)(aHi + ao); aln = *(const h8*)(aLo + ao);
      }
      acc = MFMA16(ahc, bhc, acc);
      acc = MFMA16(ahc, blc, acc);
      acc = MFMA16(alc, bhc, acc);
      bhc = bhn; blc = bln; bhn = bhf; bln = blf; ahc = ahn; alc = aln;
    }
  }
  __syncthreads();   // all A reads complete -> safe to overwrite A with O
  if (kh == 0) {
    // epilogue: C/D layout col=lane&31, row=(r&3)+8*(r>>2)+4*(lane>>5)
    int n = nt * 32 + (lane & 31);
    float bs = bias[n];
    int t2 = n >> 4, kg = (n >> 3) & 1, j = n & 7;
#pragma unroll
    for (int r = 0; r < 16; ++r) {
      int row = (r & 3) + 8 * (r >> 2) + 4 * (lane >> 5);
      int m = mt * 32 + row;
      float v = acc[r] + bs;
      v = (ACT == 0) ? fmaxf(v, 0.0f) : (1.0f / (1.0f + __expf(-v)));
      _Float16 hi = (_Float16)v;
      _Float16 lo = (_Float16)(v - (float)hi);
      int addr = ((m >> 5) * ONKT + t2) * 528 + (m & 31) * 8 + kg * 264 + j;
      oHi[addr] = hi;
      oLo[addr] = lo;
    }
  }
  __syncthreads();
}

// ---------------------------------------------------------------------------
// Phase 1: x (fp32 HBM) @ W1 -> h1. 128-k chunks (4 chunks), double-buffered
// staging. Epilogue writes h1 OVER the (dead) x staging buffers.
// ---------------------------------------------------------------------------
__device__ __forceinline__ void phase1(
    const float* __restrict__ xg,
    const _Float16* __restrict__ bHi, const _Float16* __restrict__ bLo,
    const float* __restrict__ bias,
    _Float16* xs,                 // staging: 2 bufs x 16896 els (hi 8448 + lo 8448)
    _Float16* oHi, _Float16* oLo, // h1 planes (ONKT=16) -- alias xs bufs
    int tid, int wave, int lane)
{
  const int mt = wave & 1, nt = wave >> 1;
  f16v acc = {};
  float4 xv[2];

  auto loadx = [&](int c) {
#pragma unroll
    for (int it = 0; it < 2; ++it) {
      int flat = it * 1024 + tid;
      int row = flat >> 5, c4 = flat & 31;
      xv[it] = *(const float4*)(xg + row * 512 + c * 128 + c4 * 4);
    }
  };
  auto storex = [&](int c) {
    _Float16* sHi = xs + (c & 1) * 16896;
    _Float16* sLo = sHi + 8448;
#pragma unroll
    for (int it = 0; it < 2; ++it) {
      int flat = it * 1024 + tid;
      int row = flat >> 5, c4 = flat & 31;
      int t = c4 >> 2, kg = (c4 >> 1) & 1, j0 = (c4 & 1) * 4;
      int addr = ((row >> 5) * 8 + t) * 528 + (row & 31) * 8 + kg * 264 + j0;
      float4 v = xv[it];
      h4 hi, lo;
      hi[0] = (_Float16)v.x; lo[0] = (_Float16)(v.x - (float)hi[0]);
      hi[1] = (_Float16)v.y; lo[1] = (_Float16)(v.y - (float)hi[1]);
      hi[2] = (_Float16)v.z; lo[2] = (_Float16)(v.z - (float)hi[2]);
      hi[3] = (_Float16)v.w; lo[3] = (_Float16)(v.w - (float)hi[3]);
      *(h4*)(sHi + addr) = hi;
      *(h4*)(sLo + addr) = lo;
    }
  };

  // B prefetch depth-2 over the full 32-t plane (rotation carries across chunks)
  h8 bhc, blc, bhn, bln;
  { int bo = frag_roff(lane, nt, 0, 32);
    bhc = *(const h8*)(bHi + bo); blc = *(const h8*)(bLo + bo); }
  { int bo = frag_roff(lane, nt, 1, 32);
    bhn = *(const h8*)(bHi + bo); bln = *(const h8*)(bLo + bo); }

  loadx(0);
  storex(0);
  __syncthreads();
  for (int c = 0; c < 4; ++c) {
    if (c < 3) loadx(c + 1);   // HBM loads in flight across the chunk's MFMA
    const _Float16* sHi = xs + (c & 1) * 16896;
    const _Float16* sLo = sHi + 8448;
    h8 ahc, alc;
    { int ao = frag_roff(lane, mt, 0, 8);
      ahc = *(const h8*)(sHi + ao); alc = *(const h8*)(sLo + ao); }
#pragma unroll
    for (int t = 0; t < 8; ++t) {
      int tg = c * 8 + t;
      h8 bhf, blf, ahn, aln;
      if (tg + 2 < 32) {
        int bo = frag_roff(lane, nt, tg + 2, 32);
        bhf = *(const h8*)(bHi + bo); blf = *(const h8*)(bLo + bo);
      }
      if (t + 1 < 8) {
        int ao = frag_roff(lane, mt, t + 1, 8);
        ahn = *(const h8*)(sHi + ao); aln = *(const h8*)(sLo + ao);
      }
      acc = MFMA16(ahc, bhc, acc);
      acc = MFMA16(ahc, blc, acc);
      acc = MFMA16(alc, bhc, acc);
      bhc = bhn; blc = bln; bhn = bhf; bln = blf; ahc = ahn; alc = aln;
    }
    if (c < 3) storex(c + 1);
    __syncthreads();
  }
  // epilogue -> h1 planes (ONKT = 16), overwriting x staging (dead)
  int n = nt * 32 + (lane & 31);
  float bs = bias[n];
  int t2 = n >> 4, kg = (n >> 3) & 1, j = n & 7;
#pragma unroll
  for (int r = 0; r < 16; ++r) {
    int row = (r & 3) + 8 * (r >> 2) + 4 * (lane >> 5);
    int m = mt * 32 + row;
    float v = fmaxf(acc[r] + bs, 0.0f);
    _Float16 hi = (_Float16)v;
    _Float16 lo = (_Float16)(v - (float)hi);
    int addr = ((m >> 5) * 16 + t2) * 528 + (m & 31) * 8 + kg * 264 + j;
    oHi[addr] = hi;
    oLo[addr] = lo;
  }
  __syncthreads();
}

#define BUFELS 33792  // total dynamic LDS elements (67584 B) -> 2 blocks/CU

__global__ __launch_bounds__(1024, 8) void bagnet_mfma(
    const float* __restrict__ gx, const float* __restrict__ gm,
    const float* __restrict__ gu,
    const float* __restrict__ gb1, const float* __restrict__ gb2,
    const float* __restrict__ gb3, const float* __restrict__ gdb1,
    const float* __restrict__ gdb2, const float* __restrict__ gD3,
    const float* __restrict__ gdb3, const float* __restrict__ gE,
    const float* __restrict__ geb, const _Float16* __restrict__ ws,
    float* __restrict__ outw, float* __restrict__ outv)
{
  extern __shared__ _Float16 lds[];
  __shared__ float sWf[64], sPart[2];
  const int tid = threadIdx.x, bag = blockIdx.x;
  const int wave = tid >> 6, lane = tid & 63;

  // LDS liveness plan (els):
  //  P1: x staging dbuf [0,33792) -> h1 hi [0,16896) lo [16896,33792)
  //  P2: h1 -> h2 in place (same planes)
  //  P3: h2 -> h  hi [0,8448)  lo [8448,16896)
  //  P4: h  -> d1 hi [16896,25344) lo [25344,33792)   (h preserved for tail)
  //  P5: d1 -> d2 hi [16896,21120) lo [21120,25344)   (in place over d1)
  phase1(gx + (size_t)bag * CROWS * IND, ws + W1HI, ws + W1LO, gb1,
         lds, lds, lds + 16896, tid, wave, lane);
  gemm_phase<16, 8, 0>(ws + W2HI, ws + W2LO, gb2, lds, lds + 16896,
                       lds, lds + 16896, wave, lane);
  gemm_phase<16, 4, 0>(ws + W3HI, ws + W3LO, gb3, lds, lds + 16896,
                       lds, lds + 8448, wave, lane);
  gemm_phase<8, 4, 1>(ws + D1HI, ws + D1LO, gdb1, lds, lds + 8448,
                      lds + 16896, lds + 25344, wave, lane);
  gemm_phase<8, 2, 1>(ws + D2HI, ws + D2LO, gdb2, lds + 16896, lds + 25344,
                      lds + 16896, lds + 21120, wave, lane);

  const _Float16* d2H = lds + 16896;
  const _Float16* d2L = lds + 21120;
  const _Float16* hH  = lds;
  const _Float16* hL  = lds + 8448;

  // -------- tail: logits + gumbel softmax + top-20 keep, wave 0 only, -------
  // -------- shuffle butterflies, zero internal barriers ---------------------
  if (wave == 0) {
    // logits: lane = bag-row; vectorized b128 reads of d2 (8 k's per load)
    float a = gdb3[0];
#pragma unroll
    for (int kg8 = 0; kg8 < 8; ++kg8) {
      int k0 = kg8 * 8;
      int addr = ((lane >> 5) * 4 + (k0 >> 4)) * 528 + (lane & 31) * 8 + ((k0 >> 3) & 1) * 264;
      h8 vh = *(const h8*)(d2H + addr);
      h8 vl = *(const h8*)(d2L + addr);
#pragma unroll
      for (int j = 0; j < 8; ++j)
        a = fmaf((float)vh[j] + (float)vl[j], gD3[k0 + j], a);
    }
    float logit = gm[(size_t)bag * CROWS + lane] * a;
    float uu = gu[(size_t)bag * CROWS + lane];
    float g = -logf(-logf(uu));
    float z = (logit + g) * (1.0f / TAUV);
    // softmax over the 64 lanes
    float mx = z;
#pragma unroll
    for (int o = 32; o; o >>= 1) mx = fmaxf(mx, __shfl_xor(mx, o));
    float ex = __expf(z - mx);
    float s = ex;
#pragma unroll
    for (int o = 32; o; o >>= 1) s += __shfl_xor(s, o);
    float w2 = ex / s;
    // stable rank (ascending, tie by index): keep iff rank >= KDROP
    int cnt = 0;
#pragma unroll 8
    for (int j = 0; j < 64; ++j) {
      float vj = __shfl(w2, j);
      cnt += (vj < w2) || (vj == w2 && j < lane);
    }
    int keep = (cnt >= KDROP) ? 1 : 0;
    // re-softmax over kept entries
    float wk = keep ? w2 : -1e30f;
    float mk = wk;
#pragma unroll
    for (int o = 32; o; o >>= 1) mk = fmaxf(mk, __shfl_xor(mk, o));
    float e2 = keep ? __expf(w2 - mk) : 0.0f;
    float s2 = e2;
#pragma unroll
    for (int o = 32; o; o >>= 1) s2 += __shfl_xor(s2, o);
    float wf = keep ? (e2 / s2) : 0.0f;
    sWf[lane] = wf;
    outw[(size_t)bag * CROWS + lane] = wf;
  }
  __syncthreads();
  // agg = w @ h ; out = agg @ E + eb   (waves 0-1, butterfly-reduced)
  if (tid < 128) {
    float a = 0.0f;
    for (int r = 0; r < CROWS; ++r) {
      int addr = ((r >> 5) * 8 + (tid >> 4)) * 528 + (r & 31) * 8 + ((tid >> 3) & 1) * 264 + (tid & 7);
      a = fmaf(sWf[r], (float)hH[addr] + (float)hL[addr], a);
    }
    float p = a * gE[tid];
#pragma unroll
    for (int o = 32; o; o >>= 1) p += __shfl_xor(p, o);
    if (lane == 0) sPart[wave] = p;
  }
  __syncthreads();
  if (tid == 0) outv[bag] = geb[0] + sPart[0] + sPart[1];
}

extern "C" void kernel_launch(void* const* d_in, const int* in_sizes, int n_in,
                              void* d_out, int out_size, void* d_ws, size_t ws_size,
                              hipStream_t stream) {
  (void)in_sizes; (void)n_in; (void)out_size; (void)ws_size;
  const float* x   = (const float*)d_in[0];
  const float* m   = (const float*)d_in[1];
  const float* u   = (const float*)d_in[2];
  const float* W1  = (const float*)d_in[3];
  const float* b1  = (const float*)d_in[4];
  const float* W2  = (const float*)d_in[5];
  const float* b2  = (const float*)d_in[6];
  const float* W3  = (const float*)d_in[7];
  const float* b3  = (const float*)d_in[8];
  const float* D1  = (const float*)d_in[9];
  const float* db1 = (const float*)d_in[10];
  const float* D2  = (const float*)d_in[11];
  const float* db2 = (const float*)d_in[12];
  const float* D3  = (const float*)d_in[13];
  const float* db3 = (const float*)d_in[14];
  const float* E   = (const float*)d_in[15];
  const float* eb  = (const float*)d_in[16];
  float* outw = (float*)d_out;
  float* outv = outw + (size_t)NBAGS * CROWS;
  _Float16* ws = (_Float16*)d_ws;

  prep_weights<<<992, 256, 0, stream>>>(W1, W2, W3, D1, D2, ws);

  const size_t smem = (size_t)BUFELS * sizeof(_Float16);  // 67584 B
  (void)hipFuncSetAttribute((const void*)bagnet_mfma,
                            hipFuncAttributeMaxDynamicSharedMemorySize, (int)smem);
  bagnet_mfma<<<NBAGS, 1024, smem, stream>>>(
      x, m, u, b1, b2, b3, db1, db2, D3, db3, E, eb, ws, outw, outv);
}

// Round 6
// 545.990 us; speedup vs baseline: 1.4908x; 1.4463x over previous
//
#include <hip/hip_runtime.h>
#include <math.h>

#define NBAGS 2048
#define CROWS 64
#define IND   512
#define TAUV  0.95f
#define KDROP 44   // int(64*0.7)

typedef _Float16 h8  __attribute__((ext_vector_type(8)));
typedef _Float16 h4  __attribute__((ext_vector_type(4)));
typedef float    f16v __attribute__((ext_vector_type(16)));

#define MFMA16(a, b, c) __builtin_amdgcn_mfma_f32_32x32x16_f16(a, b, c, 0, 0, 0)

// ---------------------------------------------------------------------------
// Fragment-order layout for an MFMA operand plane (A: [m][k], B: [n][k]).
//   addr = (tile*nkt + (k>>4))*528 + (idx&31)*8 + ((k>>3)&1)*264 + (k&7)
// ---------------------------------------------------------------------------
__device__ __forceinline__ int frag_roff(int lane, int tile, int t, int nkt) {
  return (tile * nkt + t) * 528 + (lane & 31) * 8 + (lane >> 5) * 264;
}

// ws element offsets (in _Float16 units). plane = (N/32)*nkt*528.
#define W1HI 0
#define W1LO 135168
#define W2HI 270336
#define W2LO 337920
#define W3HI 405504
#define W3LO 439296
#define D1HI 473088
#define D1LO 489984
#define D2HI 506880
#define D2LO 515328
#define WS_ELS 523776  // ~1.05 MB

__global__ __launch_bounds__(256) void prep_weights(
    const float* __restrict__ W1, const float* __restrict__ W2,
    const float* __restrict__ W3, const float* __restrict__ D1,
    const float* __restrict__ D2, _Float16* __restrict__ ws)
{
  int e = blockIdx.x * 256 + threadIdx.x;
  const float* src; int local, nlog, nkt, offH, offL;
  if (e < 131072)      { src = W1; local = e;          nlog = 8; nkt = 32; offH = W1HI; offL = W1LO; }
  else if (e < 196608) { src = W2; local = e - 131072; nlog = 8; nkt = 16; offH = W2HI; offL = W2LO; }
  else if (e < 229376) { src = W3; local = e - 196608; nlog = 7; nkt = 16; offH = W3HI; offL = W3LO; }
  else if (e < 245760) { src = D1; local = e - 229376; nlog = 7; nkt = 8;  offH = D1HI; offL = D1LO; }
  else if (e < 253952) { src = D2; local = e - 245760; nlog = 6; nkt = 8;  offH = D2HI; offL = D2LO; }
  else return;
  int k = local >> nlog;
  int n = local & ((1 << nlog) - 1);
  float w = src[local];
  _Float16 hi = (_Float16)w;
  _Float16 lo = (_Float16)(w - (float)hi);
  int addr = ((n >> 5) * nkt + (k >> 4)) * 528 + (n & 31) * 8 + ((k >> 3) & 1) * 264 + (k & 7);
  ws[offH + addr] = hi;
  ws[offL + addr] = lo;
}

// ---------------------------------------------------------------------------
// Generic phase, 16 waves, wave -> tile=(mt,nt). No K-split (co-resident
// blocks now cover latency). Output may alias input: a barrier separates
// last A-read from first epilogue write (in-place activation ping-pong).
// ---------------------------------------------------------------------------
template<int NKT_TOT, int NTILES, int ACT>   // NKT_TOT=K/16, NTILES=N/32
__device__ __forceinline__ void gemm_phase(
    const _Float16* __restrict__ bHi, const _Float16* __restrict__ bLo,
    const float* __restrict__ bias,
    const _Float16* aHi, const _Float16* aLo,
    _Float16* oHi, _Float16* oLo,
    int wave, int lane)
{
  constexpr int TILES = 2 * NTILES;
  constexpr int ONKT  = NTILES * 2;
  const int tile = wave & (TILES - 1);
  const int kh   = wave / TILES;       // kh > 0 waves idle (small phases)
  const int mt = tile & 1, nt = tile >> 1;
  f16v acc = {};
  if (kh == 0) {
    h8 bhc, blc, bhn, bln, ahc, alc;
    { int bo = frag_roff(lane, nt, 0, NKT_TOT);
      bhc = *(const h8*)(bHi + bo); blc = *(const h8*)(bLo + bo); }
    if constexpr (NKT_TOT > 1) {
      int bo = frag_roff(lane, nt, 1, NKT_TOT);
      bhn = *(const h8*)(bHi + bo); bln = *(const h8*)(bLo + bo);
    }
    { int ao = frag_roff(lane, mt, 0, NKT_TOT);
      ahc = *(const h8*)(aHi + ao); alc = *(const h8*)(aLo + ao); }
#pragma unroll
    for (int t = 0; t < NKT_TOT; ++t) {
      h8 bhf, blf, ahn, aln;
      if (t + 2 < NKT_TOT) {
        int bo = frag_roff(lane, nt, t + 2, NKT_TOT);
        bhf = *(const h8*)(bHi + bo); blf = *(const h8*)(bLo + bo);
      }
      if (t + 1 < NKT_TOT) {
        int ao = frag_roff(lane, mt, t + 1, NKT_TOT);
        ahn = *(const h8*)(aHi + ao); aln = *(const h8*)(aLo + ao);
      }
      acc = MFMA16(ahc, bhc, acc);
      acc = MFMA16(ahc, blc, acc);
      acc = MFMA16(alc, bhc, acc);
      bhc = bhn; blc = bln; bhn = bhf; bln = blf; ahc = ahn; alc = aln;
    }
  }
  __syncthreads();   // all A reads complete -> safe to overwrite A with O
  if (kh == 0) {
    // epilogue: C/D layout col=lane&31, row=(r&3)+8*(r>>2)+4*(lane>>5)
    int n = nt * 32 + (lane & 31);
    float bs = bias[n];
    int t2 = n >> 4, kg = (n >> 3) & 1, j = n & 7;
#pragma unroll
    for (int r = 0; r < 16; ++r) {
      int row = (r & 3) + 8 * (r >> 2) + 4 * (lane >> 5);
      int m = mt * 32 + row;
      float v = acc[r] + bs;
      v = (ACT == 0) ? fmaxf(v, 0.0f) : (1.0f / (1.0f + expf(-v)));
      _Float16 hi = (_Float16)v;
      _Float16 lo = (_Float16)(v - (float)hi);
      int addr = ((m >> 5) * ONKT + t2) * 528 + (m & 31) * 8 + kg * 264 + j;
      oHi[addr] = hi;
      oLo[addr] = lo;
    }
  }
  __syncthreads();
}

// ---------------------------------------------------------------------------
// Phase 1: x (fp32 HBM) @ W1 -> h1. 128-k chunks (4 chunks), double-buffered
// staging. Epilogue writes h1 OVER the (dead) x staging buffers.
// ---------------------------------------------------------------------------
__device__ __forceinline__ void phase1(
    const float* __restrict__ xg,
    const _Float16* __restrict__ bHi, const _Float16* __restrict__ bLo,
    const float* __restrict__ bias,
    _Float16* xs,                 // staging: 2 bufs x 16896 els (hi 8448 + lo 8448)
    _Float16* oHi, _Float16* oLo, // h1 planes (ONKT=16) -- alias xs bufs
    int tid, int wave, int lane)
{
  const int mt = wave & 1, nt = wave >> 1;
  f16v acc = {};
  float4 xv[2];

  auto loadx = [&](int c) {
#pragma unroll
    for (int it = 0; it < 2; ++it) {
      int flat = it * 1024 + tid;
      int row = flat >> 5, c4 = flat & 31;
      xv[it] = *(const float4*)(xg + row * 512 + c * 128 + c4 * 4);
    }
  };
  auto storex = [&](int c) {
    _Float16* sHi = xs + (c & 1) * 16896;
    _Float16* sLo = sHi + 8448;
#pragma unroll
    for (int it = 0; it < 2; ++it) {
      int flat = it * 1024 + tid;
      int row = flat >> 5, c4 = flat & 31;
      int t = c4 >> 2, kg = (c4 >> 1) & 1, j0 = (c4 & 1) * 4;
      int addr = ((row >> 5) * 8 + t) * 528 + (row & 31) * 8 + kg * 264 + j0;
      float4 v = xv[it];
      h4 hi, lo;
      hi[0] = (_Float16)v.x; lo[0] = (_Float16)(v.x - (float)hi[0]);
      hi[1] = (_Float16)v.y; lo[1] = (_Float16)(v.y - (float)hi[1]);
      hi[2] = (_Float16)v.z; lo[2] = (_Float16)(v.z - (float)hi[2]);
      hi[3] = (_Float16)v.w; lo[3] = (_Float16)(v.w - (float)hi[3]);
      *(h4*)(sHi + addr) = hi;
      *(h4*)(sLo + addr) = lo;
    }
  };

  // B prefetch depth-2 over the full 32-t plane (rotation carries across chunks)
  h8 bhc, blc, bhn, bln;
  { int bo = frag_roff(lane, nt, 0, 32);
    bhc = *(const h8*)(bHi + bo); blc = *(const h8*)(bLo + bo); }
  { int bo = frag_roff(lane, nt, 1, 32);
    bhn = *(const h8*)(bHi + bo); bln = *(const h8*)(bLo + bo); }

  loadx(0);
  storex(0);
  __syncthreads();
  for (int c = 0; c < 4; ++c) {
    if (c < 3) loadx(c + 1);   // HBM loads in flight across the chunk's MFMA
    const _Float16* sHi = xs + (c & 1) * 16896;
    const _Float16* sLo = sHi + 8448;
    h8 ahc, alc;
    { int ao = frag_roff(lane, mt, 0, 8);
      ahc = *(const h8*)(sHi + ao); alc = *(const h8*)(sLo + ao); }
#pragma unroll
    for (int t = 0; t < 8; ++t) {
      int tg = c * 8 + t;
      h8 bhf, blf, ahn, aln;
      if (tg + 2 < 32) {
        int bo = frag_roff(lane, nt, tg + 2, 32);
        bhf = *(const h8*)(bHi + bo); blf = *(const h8*)(bLo + bo);
      }
      if (t + 1 < 8) {
        int ao = frag_roff(lane, mt, t + 1, 8);
        ahn = *(const h8*)(sHi + ao); aln = *(const h8*)(sLo + ao);
      }
      acc = MFMA16(ahc, bhc, acc);
      acc = MFMA16(ahc, blc, acc);
      acc = MFMA16(alc, bhc, acc);
      bhc = bhn; blc = bln; bhn = bhf; bln = blf; ahc = ahn; alc = aln;
    }
    if (c < 3) storex(c + 1);
    __syncthreads();
  }
  // epilogue -> h1 planes (ONKT = 16), overwriting x staging (dead)
  int n = nt * 32 + (lane & 31);
  float bs = bias[n];
  int t2 = n >> 4, kg = (n >> 3) & 1, j = n & 7;
#pragma unroll
  for (int r = 0; r < 16; ++r) {
    int row = (r & 3) + 8 * (r >> 2) + 4 * (lane >> 5);
    int m = mt * 32 + row;
    float v = fmaxf(acc[r] + bs, 0.0f);
    _Float16 hi = (_Float16)v;
    _Float16 lo = (_Float16)(v - (float)hi);
    int addr = ((m >> 5) * 16 + t2) * 528 + (m & 31) * 8 + kg * 264 + j;
    oHi[addr] = hi;
    oLo[addr] = lo;
  }
  __syncthreads();
}

#define BUFELS 33792  // total dynamic LDS elements (67584 B) -> 2 blocks/CU

__global__ __launch_bounds__(1024, 8) void bagnet_mfma(
    const float* __restrict__ gx, const float* __restrict__ gm,
    const float* __restrict__ gu,
    const float* __restrict__ gb1, const float* __restrict__ gb2,
    const float* __restrict__ gb3, const float* __restrict__ gdb1,
    const float* __restrict__ gdb2, const float* __restrict__ gD3,
    const float* __restrict__ gdb3, const float* __restrict__ gE,
    const float* __restrict__ geb, const _Float16* __restrict__ ws,
    float* __restrict__ outw, float* __restrict__ outv)
{
  extern __shared__ _Float16 lds[];
  __shared__ float sZ[64], sEx[64], sW2s[64], sKeep[64], sE2[64], sWf[64], sRed[128];
  const int tid = threadIdx.x, bag = blockIdx.x;
  const int wave = tid >> 6, lane = tid & 63;

  // LDS liveness plan (els):
  //  P1: x staging dbuf [0,33792) -> h1 hi [0,16896) lo [16896,33792)
  //  P2: h1 -> h2 in place (same planes)
  //  P3: h2 -> h  hi [0,8448)  lo [8448,16896)
  //  P4: h  -> d1 hi [16896,25344) lo [25344,33792)   (h preserved for tail)
  //  P5: d1 -> d2 hi [16896,21120) lo [21120,25344)   (in place over d1)
  phase1(gx + (size_t)bag * CROWS * IND, ws + W1HI, ws + W1LO, gb1,
         lds, lds, lds + 16896, tid, wave, lane);
  gemm_phase<16, 8, 0>(ws + W2HI, ws + W2LO, gb2, lds, lds + 16896,
                       lds, lds + 16896, wave, lane);
  gemm_phase<16, 4, 0>(ws + W3HI, ws + W3LO, gb3, lds, lds + 16896,
                       lds, lds + 8448, wave, lane);
  gemm_phase<8, 4, 1>(ws + D1HI, ws + D1LO, gdb1, lds, lds + 8448,
                      lds + 16896, lds + 25344, wave, lane);
  gemm_phase<8, 2, 1>(ws + D2HI, ws + D2LO, gdb2, lds + 16896, lds + 25344,
                      lds + 16896, lds + 21120, wave, lane);

  const _Float16* d2H = lds + 16896;
  const _Float16* d2L = lds + 21120;
  const _Float16* hH  = lds;
  const _Float16* hL  = lds + 8448;

  // ---------------- logits + gumbel softmax (fp32, verified tail) ----------
  if (tid < CROWS) {
    float a = gdb3[0];
    for (int k = 0; k < 64; ++k) {
      int addr = ((tid >> 5) * 4 + (k >> 4)) * 528 + (tid & 31) * 8 + ((k >> 3) & 1) * 264 + (k & 7);
      a = fmaf((float)d2H[addr] + (float)d2L[addr], gD3[k], a);
    }
    float logit = gm[(size_t)bag * CROWS + tid] * a;
    float uu = gu[(size_t)bag * CROWS + tid];
    float g = -logf(-logf(uu));
    sZ[tid] = (logit + g) * (1.0f / TAUV);
  }
  __syncthreads();
  if (tid < CROWS) {
    float mx = -1e30f;
    for (int j = 0; j < CROWS; ++j) mx = fmaxf(mx, sZ[j]);
    sEx[tid] = expf(sZ[tid] - mx);
  }
  __syncthreads();
  float w2 = 0.0f;
  if (tid < CROWS) {
    float s = 0.0f;
    for (int j = 0; j < CROWS; ++j) s += sEx[j];
    w2 = sEx[tid] / s;
    sW2s[tid] = w2;
  }
  __syncthreads();
  // stable top-20 keep (rank >= 44 ascending, stable tie by index)
  int keep = 0;
  if (tid < CROWS) {
    int cnt = 0;
    for (int j = 0; j < CROWS; ++j) {
      float vj = sW2s[j];
      cnt += (vj < w2) || (vj == w2 && j < tid);
    }
    keep = (cnt >= KDROP) ? 1 : 0;
    sKeep[tid] = (float)keep;
  }
  __syncthreads();
  float e2 = 0.0f;
  if (tid < CROWS) {
    float mk = -1e30f;
    for (int j = 0; j < CROWS; ++j)
      if (sKeep[j] > 0.5f) mk = fmaxf(mk, sW2s[j]);
    e2 = keep ? expf(w2 - mk) : 0.0f;
    sE2[tid] = e2;
  }
  __syncthreads();
  if (tid < CROWS) {
    float s2 = 0.0f;
    for (int j = 0; j < CROWS; ++j) s2 += sE2[j];
    float wf = keep ? (e2 / s2) : 0.0f;
    sWf[tid] = wf;
    outw[(size_t)bag * CROWS + tid] = wf;
  }
  __syncthreads();
  // agg = w @ h ; out = agg @ E + eb
  if (tid < 128) {
    float a = 0.0f;
    for (int r = 0; r < CROWS; ++r) {
      int addr = ((r >> 5) * 8 + (tid >> 4)) * 528 + (r & 31) * 8 + ((tid >> 3) & 1) * 264 + (tid & 7);
      a = fmaf(sWf[r], (float)hH[addr] + (float)hL[addr], a);
    }
    sRed[tid] = a * gE[tid];
  }
  __syncthreads();
  if (tid == 0) {
    float s = geb[0];
    for (int j = 0; j < 128; ++j) s += sRed[j];
    outv[bag] = s;
  }
}

extern "C" void kernel_launch(void* const* d_in, const int* in_sizes, int n_in,
                              void* d_out, int out_size, void* d_ws, size_t ws_size,
                              hipStream_t stream) {
  (void)in_sizes; (void)n_in; (void)out_size; (void)ws_size;
  const float* x   = (const float*)d_in[0];
  const float* m   = (const float*)d_in[1];
  const float* u   = (const float*)d_in[2];
  const float* W1  = (const float*)d_in[3];
  const float* b1  = (const float*)d_in[4];
  const float* W2  = (const float*)d_in[5];
  const float* b2  = (const float*)d_in[6];
  const float* W3  = (const float*)d_in[7];
  const float* b3  = (const float*)d_in[8];
  const float* D1  = (const float*)d_in[9];
  const float* db1 = (const float*)d_in[10];
  const float* D2  = (const float*)d_in[11];
  const float* db2 = (const float*)d_in[12];
  const float* D3  = (const float*)d_in[13];
  const float* db3 = (const float*)d_in[14];
  const float* E   = (const float*)d_in[15];
  const float* eb  = (const float*)d_in[16];
  float* outw = (float*)d_out;
  float* outv = outw + (size_t)NBAGS * CROWS;
  _Float16* ws = (_Float16*)d_ws;

  prep_weights<<<992, 256, 0, stream>>>(W1, W2, W3, D1, D2, ws);

  const size_t smem = (size_t)BUFELS * sizeof(_Float16);  // 67584 B
  (void)hipFuncSetAttribute((const void*)bagnet_mfma,
                            hipFuncAttributeMaxDynamicSharedMemorySize, (int)smem);
  bagnet_mfma<<<NBAGS, 1024, smem, stream>>>(
      x, m, u, b1, b2, b3, db1, db2, D3, db3, E, eb, ws, outw, outv);
}